// Round 6
// baseline (1325.733 us; speedup 1.0000x reference)
//
#include <hip/hip_runtime.h>
#include <hip/hip_bf16.h>
#include <math.h>

#define N_NODES 50000
#define DEG 16
#define FIN 256
#define FOUT 128
#define HID 128
#define FG 512            // 4*HID
#define NEDGE (N_NODES*DEG)
#define NCHUNK (N_NODES/16)   // 3125 exactly

#define K5_WAVES 7
#define K5_THREADS (K5_WAVES*64)
#define K5_LDS (131072 + K5_WAVES*4096)   // B-table + per-wave h transpose buffers

typedef __bf16 bf16x8 __attribute__((ext_vector_type(8)));
typedef float  f32x4  __attribute__((ext_vector_type(4)));

// ---------------- helpers ----------------
static __device__ __forceinline__ float u2f(unsigned int u){ union {unsigned int u; float f;} v; v.u=u; return v.f; }
static __device__ __forceinline__ unsigned int f2u(float f){ union {float f; unsigned int u;} v; v.f=f; return v.u; }
static __device__ __forceinline__ unsigned short f2bfu(float f){  // RNE float->bf16 bits
  unsigned int u = f2u(f);
  unsigned int r = u + 0x7fffu + ((u >> 16) & 1u);
  return (unsigned short)(r >> 16);
}
static __device__ __forceinline__ float bflo(unsigned int u){ return u2f(u << 16); }
static __device__ __forceinline__ float bfhi(unsigned int u){ return u2f(u & 0xffff0000u); }
static __device__ __forceinline__ float sigm(float x){ return 1.f/(1.f + __expf(-x)); }
static __device__ __forceinline__ float tanhx(float x){ return 1.f - 2.f/(__expf(2.f*x) + 1.f); }

union FU { bf16x8 bf; unsigned short us[8]; uint4 u4; };

// ---------------- K0: init global-max key + steal counter ----------------
__global__ void k0_init(unsigned int* __restrict__ gmax_key, unsigned int* __restrict__ cnt){
  if (threadIdx.x == 0) { *gmax_key = 0u; *cnt = 0u; }
}

// ---------------- KA: x -> bf16 hi/lo planes ----------------
__global__ __launch_bounds__(256) void k_cvt(
    const float* __restrict__ x, unsigned short* __restrict__ xh, unsigned short* __restrict__ xl)
{
  const int idx = blockIdx.x*256 + threadIdx.x;     // float4 granules
  if (idx >= (N_NODES*FIN)/4) return;
  const float4 v = ((const float4*)x)[idx];
  ushort4 h, l;
  h.x = f2bfu(v.x); l.x = f2bfu(v.x - u2f((unsigned)h.x << 16));
  h.y = f2bfu(v.y); l.y = f2bfu(v.y - u2f((unsigned)h.y << 16));
  h.z = f2bfu(v.z); l.z = f2bfu(v.z - u2f((unsigned)h.z << 16));
  h.w = f2bfu(v.w); l.w = f2bfu(v.w - u2f((unsigned)h.w << 16));
  ((ushort4*)xh)[idx] = h;
  ((ushort4*)xl)[idx] = l;
}

// ---------------- KW: weight converts + v = W^T a (double) + w_hh B-frag pack ----------------
// blocks 0..255: Wcomb rows -> Wch/Wcl ; 256..511: wih -> wihh/wihl ; 512: v=W^T a
// blocks 513..768: whh [512,128] -> Pl bf16 packed per MFMA B-fragment, gate-major tiles:
//   element (row=g*128+f, k): ct=g*8+(f>>4), kt=k>>5, lane=((k>>3)&3)*16+(f&15), j=k&7
//   Pl[((ct*4+kt)*64 + lane)*8 + j]
__global__ __launch_bounds__(256) void k_w(
    const float* __restrict__ Wp, const float* __restrict__ Ws,
    const float* __restrict__ wih, const float* __restrict__ whh,
    const float* __restrict__ a_src, const float* __restrict__ a_trg,
    unsigned short* __restrict__ Wch, unsigned short* __restrict__ Wcl,
    unsigned short* __restrict__ wihh, unsigned short* __restrict__ wihl,
    unsigned short* __restrict__ Pl,
    double* __restrict__ vsrc, double* __restrict__ vtrg)
{
  const int b = blockIdx.x, tid = threadIdx.x;
  if (b < 256) {
    const float* src = (b < 128) ? (Wp + b*FIN) : (Ws + (b-128)*FIN);
    const float v = src[tid];
    const unsigned short h = f2bfu(v);
    Wch[b*FIN + tid] = h;
    Wcl[b*FIN + tid] = f2bfu(v - u2f((unsigned)h << 16));
  } else if (b < 512) {
    const int row = (b-256)*2 + (tid >> 7);
    const int k   = tid & 127;
    const float v = wih[row*HID + k];
    const unsigned short h = f2bfu(v);
    wihh[row*HID + k] = h;
    wihl[row*HID + k] = f2bfu(v - u2f((unsigned)h << 16));
  } else if (b == 512) {
    const int k = tid;
    double s1 = 0.0, s2 = 0.0;
    for (int i = 0; i < FOUT; ++i) {
      const double w = (double)Wp[i*FIN + k];
      s1 += (double)a_src[i] * w;
      s2 += (double)a_trg[i] * w;
    }
    vsrc[k] = s1; vtrg[k] = s2;
  } else {
    const int idx = (b-513)*256 + tid;        // one whh element
    const int row = idx >> 7, k = idx & 127;  // row = g*128+f
    const int g = row >> 7, f = row & 127;
    const int ct = g*8 + (f >> 4);
    const int kt = k >> 5;
    const int lane = ((k >> 3) & 3)*16 + (f & 15);
    const int j = k & 7;
    Pl[((ct*4 + kt)*64 + lane)*8 + j] = f2bfu(whh[row*HID + k]);
  }
}

// ---------------- KS: s_src/s_trg = x @ v (double) ----------------
__global__ __launch_bounds__(256) void k_s(
    const float* __restrict__ x, const double* __restrict__ vsrc, const double* __restrict__ vtrg,
    double* __restrict__ ssrc, double* __restrict__ strg)
{
  const int n = blockIdx.x*256 + threadIdx.x;
  if (n >= N_NODES) return;
  double ss = 0.0, st = 0.0;
  for (int k = 0; k < FIN; k += 4) {
    const float4 xv = *(const float4*)&x[n*FIN + k];
    ss += xv.x*vsrc[k] + xv.y*vsrc[k+1] + xv.z*vsrc[k+2] + xv.w*vsrc[k+3];
    st += xv.x*vtrg[k] + xv.y*vtrg[k+1] + xv.z*vtrg[k+2] + xv.w*vtrg[k+3];
  }
  ssrc[n] = ss; strg[n] = st;
}

// ---------------- KG: split-bf16 MFMA GEMM, 128x64 tile (unchanged) ----------------
template<int KD, int MODE>
__global__ __launch_bounds__(256) void kgemm(
    const unsigned short* __restrict__ Ah_g, const unsigned short* __restrict__ Al_g,
    const unsigned short* __restrict__ Bh_g, const unsigned short* __restrict__ Bl_g,
    const float* __restrict__ bias, float* __restrict__ outf,
    unsigned short* __restrict__ o_h, unsigned short* __restrict__ o_l)
{
  __shared__ unsigned short At[2][128*64];
  __shared__ unsigned short Bt[2][64*64];
  const int tid = threadIdx.x;
  const int bm = blockIdx.x, bn = blockIdx.y;
  const int r0 = bm*128;
  const int wave = tid >> 6, lane = tid & 63, c = lane & 15, q = lane >> 4;
  const int srow = tid >> 3, sg = tid & 7;

  f32x4 acc[2][4];
  #pragma unroll
  for (int rt = 0; rt < 2; ++rt)
    #pragma unroll
    for (int ct = 0; ct < 4; ++ct) acc[rt][ct] = (f32x4){0.f,0.f,0.f,0.f};

  for (int kt = 0; kt < KD/64; ++kt) {
    const int k0 = kt*64;
    __syncthreads();
    #pragma unroll
    for (int rr = 0; rr < 4; ++rr) {
      const int row = rr*32 + srow;
      int grow = r0 + row; if (grow >= N_NODES) grow = N_NODES-1;
      const int ga = grow*KD + k0 + sg*8;
      const int la = row*64 + (((sg ^ (row & 7))) << 3);
      *(uint4*)&At[0][la] = *(const uint4*)&Ah_g[ga];
      *(uint4*)&At[1][la] = *(const uint4*)&Al_g[ga];
    }
    #pragma unroll
    for (int rr = 0; rr < 2; ++rr) {
      const int row = rr*32 + srow;
      int wr;
      if (MODE == 0) wr = bn*64 + row;
      else { const int j = bn*64 + row; wr = (j & 3)*HID + (j >> 2); }
      const int ga = wr*KD + k0 + sg*8;
      const int la = row*64 + (((sg ^ (row & 7))) << 3);
      *(uint4*)&Bt[0][la] = *(const uint4*)&Bh_g[ga];
      *(uint4*)&Bt[1][la] = *(const uint4*)&Bl_g[ga];
    }
    __syncthreads();

    #pragma unroll
    for (int s = 0; s < 2; ++s) {
      FU Af[2][2], Bf[4][2];
      #pragma unroll
      for (int rt = 0; rt < 2; ++rt) {
        const int row = wave*32 + rt*16 + c;
        const int ad = row*64 + (((((s<<2)+q) ^ (row & 7))) << 3);
        Af[rt][0].u4 = *(const uint4*)&At[0][ad];
        Af[rt][1].u4 = *(const uint4*)&At[1][ad];
      }
      #pragma unroll
      for (int ct = 0; ct < 4; ++ct) {
        const int row = ct*16 + c;
        const int ad = row*64 + (((((s<<2)+q) ^ (row & 7))) << 3);
        Bf[ct][0].u4 = *(const uint4*)&Bt[0][ad];
        Bf[ct][1].u4 = *(const uint4*)&Bt[1][ad];
      }
      #pragma unroll
      for (int rt = 0; rt < 2; ++rt)
        #pragma unroll
        for (int ct = 0; ct < 4; ++ct) {
          acc[rt][ct] = __builtin_amdgcn_mfma_f32_16x16x32_bf16(Af[rt][0].bf, Bf[ct][0].bf, acc[rt][ct], 0,0,0);
          acc[rt][ct] = __builtin_amdgcn_mfma_f32_16x16x32_bf16(Af[rt][1].bf, Bf[ct][0].bf, acc[rt][ct], 0,0,0);
          acc[rt][ct] = __builtin_amdgcn_mfma_f32_16x16x32_bf16(Af[rt][0].bf, Bf[ct][1].bf, acc[rt][ct], 0,0,0);
        }
    }
  }
  __syncthreads();

  if (MODE == 0 && bn >= 2) {
    #pragma unroll
    for (int ct = 0; ct < 4; ++ct) {
      const int col = bn*64 + ct*16 + c - 128;
      const float bv = bias[col];
      #pragma unroll
      for (int rt = 0; rt < 2; ++rt)
        #pragma unroll
        for (int i = 0; i < 4; ++i) {
          const int row = r0 + wave*32 + rt*16 + q*4 + i;
          if (row < N_NODES) outf[row*FOUT + col] = acc[rt][ct][i] + bv;
        }
    }
  } else {
    #pragma unroll
    for (int rt = 0; rt < 2; ++rt)
      #pragma unroll
      for (int ct = 0; ct < 4; ++ct)
        #pragma unroll
        for (int i = 0; i < 4; ++i) {
          const int lrow = wave*32 + rt*16 + q*4 + i;
          const int lcol = ct*16 + c;
          const float v = acc[rt][ct][i];
          const unsigned short h = f2bfu(v);
          At[0][lrow*64 + lcol] = h;
          if (MODE == 0) At[1][lrow*64 + lcol] = f2bfu(v - u2f((unsigned)h << 16));
        }
    __syncthreads();
    const int ncols = (MODE == 0) ? FOUT : FG;
    #pragma unroll
    for (int rr = 0; rr < 4; ++rr) {
      const int row = rr*32 + srow;
      const int grow = r0 + row;
      if (grow < N_NODES) {
        const int dst = grow*ncols + bn*64 + sg*8;
        *(uint4*)&o_h[dst] = *(const uint4*)&At[0][row*64 + sg*8];
        if (MODE == 0) *(uint4*)&o_l[dst] = *(const uint4*)&At[1][row*64 + sg*8];
      }
    }
  }
}

// ---------------- K3: edge scores (double) + global max ----------------
__global__ __launch_bounds__(256) void k3_scores(
    const double* __restrict__ ssrc, const double* __restrict__ strg,
    const int* __restrict__ esrc, const int* __restrict__ etrg,
    double* __restrict__ scod, unsigned int* __restrict__ gmax_key)
{
  const int n = blockIdx.x*256 + threadIdx.x;
  float lmax = -3.0e38f;
  if (n < N_NODES) {
    const double stn = strg[etrg[n*DEG]];
    #pragma unroll
    for (int j = 0; j < DEG; ++j) {
      const int e = n*DEG + j;
      double sc = ssrc[esrc[e]] + stn;
      sc = (sc > 0.0) ? sc : 0.2*sc;
      scod[e] = sc;
      lmax = fmaxf(lmax, (float)sc);
    }
  }
  #pragma unroll
  for (int off = 32; off > 0; off >>= 1)
    lmax = fmaxf(lmax, __shfl_down(lmax, off, 64));
  __shared__ float wmax[4];
  if ((threadIdx.x & 63) == 0) wmax[threadIdx.x >> 6] = lmax;
  __syncthreads();
  if (threadIdx.x == 0) {
    const float mv = fmaxf(fmaxf(wmax[0], wmax[1]), fmaxf(wmax[2], wmax[3]));
    const unsigned int u = f2u(mv);
    const unsigned int key = (u & 0x80000000u) ? ~u : (u | 0x80000000u);
    atomicMax(gmax_key, key);
  }
}

// ---------------- K4: softmax att + descending rank -> packed sa[chunk][t][node]={src,att} ----------------
__global__ __launch_bounds__(256) void k4_att(
    const double* __restrict__ scod, const int* __restrict__ esrc,
    const unsigned int* __restrict__ gmax_key,
    uint2* __restrict__ sa)
{
  const int n = blockIdx.x*256 + threadIdx.x;
  if (n >= N_NODES) return;
  const unsigned int key = *gmax_key;
  const unsigned int u = (key & 0x80000000u) ? (key ^ 0x80000000u) : ~key;
  const float gmax = u2f(u);

  double sc[DEG]; float av[DEG]; int si[DEG];
  float sum = 0.f;
  #pragma unroll
  for (int j = 0; j < DEG; ++j) {
    sc[j] = scod[n*DEG + j];
    av[j] = __expf((float)sc[j] - gmax);
    sum  += av[j];
    si[j] = esrc[n*DEG + j];
  }
  const float inv = 1.f/(sum + 1e-16f);
  const int chunk = n >> 4, node = n & 15;
  #pragma unroll
  for (int j = 0; j < DEG; ++j) {
    int r = 0;
    #pragma unroll
    for (int k = 0; k < DEG; ++k)
      r += (sc[k] > sc[j]) || (sc[k] == sc[j] && k > j);
    sa[chunk*256 + r*16 + node] = make_uint2((unsigned)si[j], f2u(av[j]*inv));
  }
}

// ---------------- K5: wave-private MFMA LSTM, whh streamed from LDS, work-stealing ----------------
// 1 wave = 1 chunk (16 nodes x 512 gate-cols). No __syncthreads in the t-loop.
// Gate-major tiles ct=g*8+fb: lane(c,q) holds gates g of (node=q*4+d, f=fb*16+c)
// -> all 4 gates of a (node,f) in one lane. whh B-frags: 128 ds_read_b128/step
// from the 128KB LDS table (nothing for the allocator to remat). h transposed
// C->A via per-wave 4KB LDS buffer with r2's verified XOR swizzle; per-wave DS
// ordering makes it barrier-free. xg gathered as uint2 (imm offsets), sa
// prefetched 2 steps ahead. Wave-level atomic work stealing over 3125 chunks.
__global__ __attribute__((amdgpu_flat_work_group_size(K5_THREADS, K5_THREADS), amdgpu_waves_per_eu(1, 2)))
void k5_lstm(
    const unsigned short* __restrict__ Gu, const unsigned short* __restrict__ Pl,
    const float* __restrict__ bih, const float* __restrict__ bhh,
    const uint2* __restrict__ sa, unsigned int* __restrict__ cnt,
    float* __restrict__ out)
{
  extern __shared__ unsigned char smem[];
  unsigned short* Bt = (unsigned short*)smem;                    // [32ct][4kt][64lane][8]
  const int tid  = threadIdx.x;
  const int wave = tid >> 6, lane = tid & 63;
  const int c = lane & 15, q = lane >> 4;
  unsigned short* hb = (unsigned short*)(smem + 131072) + wave*2048;  // [16node][128] swizzled

  // cooperative B-table load (128 KB), once
  {
    const uint4* src = (const uint4*)Pl;
    uint4* dst = (uint4*)Bt;
    for (int i = tid; i < 8192; i += K5_THREADS) dst[i] = src[i];
  }
  // bsum packed bf16: bsp[fb*2 + (g>>1)] = {g even | g odd}
  unsigned int bsp[16];
  #pragma unroll
  for (int fb = 0; fb < 8; ++fb) {
    const int f = fb*16 + c;
    #pragma unroll
    for (int gh = 0; gh < 2; ++gh) {
      const float b0 = bih[(gh*2  )*HID + f] + bhh[(gh*2  )*HID + f];
      const float b1 = bih[(gh*2+1)*HID + f] + bhh[(gh*2+1)*HID + f];
      bsp[fb*2+gh] = (unsigned)f2bfu(b0) | ((unsigned)f2bfu(b1) << 16);
    }
  }
  int aoff[4];
  #pragma unroll
  for (int kt = 0; kt < 4; ++kt)
    aoff[kt] = c*128 + (((kt*4 + q) ^ c) & 15)*8;
  __syncthreads();   // B-table ready; the only barrier

  const uint4* Bt4 = (const uint4*)Bt;
  const char* Gbase = (const char*)Gu + c*8;

  for (;;) {
    unsigned my;
    if (lane == 0) my = atomicAdd(cnt, 1u);
    my = (unsigned)__builtin_amdgcn_readfirstlane((int)my);
    if (my >= NCHUNK) break;
    const int sab = (int)my * 256;

    // prefetch sa[0], issue xg[0], prefetch sa[1]
    uint2 sn[4]; float attv[4]; uint2 xg[4][8];
    #pragma unroll
    for (int d = 0; d < 4; ++d) sn[d] = sa[sab + q*4 + d];
    #pragma unroll
    for (int d = 0; d < 4; ++d) {
      const char* base = Gbase + (size_t)sn[d].x * 1024;
      attv[d] = u2f(sn[d].y);
      #pragma unroll
      for (int fb = 0; fb < 8; ++fb) xg[d][fb] = *(const uint2*)(base + fb*128);
    }
    #pragma unroll
    for (int d = 0; d < 4; ++d) sn[d] = sa[sab + 16 + q*4 + d];

    f32x4 cst[8];
    #pragma unroll
    for (int fb = 0; fb < 8; ++fb) cst[fb] = (f32x4){0.f,0.f,0.f,0.f};

    #pragma unroll 1
    for (int t = 0; t < DEG; ++t) {
      // A-frags from previous h (written at tail of t-1; per-wave DS is in-order)
      FU A[4];
      if (t > 0) {
        #pragma unroll
        for (int kt = 0; kt < 4; ++kt) A[kt].u4 = *(const uint4*)(hb + aoff[kt]);
      }
      // acc init: bias + att*xg   (acc[g][fb], element d = node q*4+d)
      f32x4 acc[4][8];
      #pragma unroll
      for (int fb = 0; fb < 8; ++fb) {
        const float b0 = bflo(bsp[fb*2]),   b1 = bfhi(bsp[fb*2]);
        const float b2 = bflo(bsp[fb*2+1]), b3 = bfhi(bsp[fb*2+1]);
        #pragma unroll
        for (int d = 0; d < 4; ++d) {
          const uint2 xv = xg[d][fb];
          acc[0][fb][d] = b0 + attv[d]*bflo(xv.x);
          acc[1][fb][d] = b1 + attv[d]*bfhi(xv.x);
          acc[2][fb][d] = b2 + attv[d]*bflo(xv.y);
          acc[3][fb][d] = b3 + attv[d]*bfhi(xv.y);
        }
      }
      // recurrent matmul: 32 tiles x 4 k-frags, B streamed from LDS
      if (t > 0) {
        #pragma unroll
        for (int ct = 0; ct < 32; ++ct) {
          const int g = ct >> 3, fb = ct & 7;
          #pragma unroll
          for (int kt = 0; kt < 4; ++kt) {
            FU Bf; Bf.u4 = Bt4[(ct*4 + kt)*64 + lane];
            acc[g][fb] = __builtin_amdgcn_mfma_f32_16x16x32_bf16(A[kt].bf, Bf.bf, acc[g][fb], 0, 0, 0);
          }
        }
      }
      // gates -> c,h ; write h to transpose buffer (or output at t=15)
      #pragma unroll
      for (int fb = 0; fb < 8; ++fb) {
        #pragma unroll
        for (int d = 0; d < 4; ++d) {
          const float ig = sigm (acc[0][fb][d]);
          const float fg = sigm (acc[1][fb][d]);
          const float gg = tanhx(acc[2][fb][d]);
          const float og = sigm (acc[3][fb][d]);
          const float cn = fg*cst[fb][d] + ig*gg;
          cst[fb][d] = cn;
          const float h = og*tanhx(cn);
          if (t < DEG-1) {
            const int node = q*4 + d;
            const int f = fb*16 + c;
            hb[node*128 + (((f >> 3) ^ node) & 15)*8 + (f & 7)] = f2bfu(h);
          } else {
            const int row = (int)my*16 + q*4 + d;
            const float v = h + out[row*HID + fb*16 + c];
            out[row*HID + fb*16 + c] = (v > 0.f) ? v : 0.01f*v;
          }
        }
      }
      // tail: issue xg for t+1 from sn; prefetch sa[t+2]
      if (t < DEG-1) {
        #pragma unroll
        for (int d = 0; d < 4; ++d) {
          const char* base = Gbase + (size_t)sn[d].x * 1024;
          attv[d] = u2f(sn[d].y);
          #pragma unroll
          for (int fb = 0; fb < 8; ++fb) xg[d][fb] = *(const uint2*)(base + fb*128);
        }
        if (t < DEG-2) {
          #pragma unroll
          for (int d = 0; d < 4; ++d) sn[d] = sa[sab + (t+2)*16 + q*4 + d];
        }
      }
    }
  }
}

// ---------------- launch ----------------
// ws layout (bytes):
//  gmax @0, cnt @64 (256 total) | xh @256 (25.6M) | xl @25600256 (25.6M)  [G aliases xh+xl]
//  projh @51200256 (12.8M) [scod aliases] | projl @64000256 (12.8M) [sa (6.4M) aliases]
//  Wch @76800256  Wcl @76931328  wihh @77062400  wihl @77193472 (128K each)
//  vsrc @77324544 vtrg @77326592 (2K) | ssrc @77328640 strg @77728640 (400K each)
//  Pl @78128640 (128K)  -> end ~78.26 MB
extern "C" void kernel_launch(void* const* d_in, const int* in_sizes, int n_in,
                              void* d_out, int out_size, void* d_ws, size_t ws_size,
                              hipStream_t stream)
{
  (void)in_sizes; (void)n_in; (void)out_size; (void)ws_size;
  const float* x     = (const float*)d_in[0];
  const float* Wp    = (const float*)d_in[1];
  const float* a_src = (const float*)d_in[2];
  const float* a_trg = (const float*)d_in[3];
  const float* Ws    = (const float*)d_in[4];
  const float* bias  = (const float*)d_in[5];
  const float* wih_b = (const float*)d_in[10];
  const float* whh_b = (const float*)d_in[11];
  const float* bih_b = (const float*)d_in[12];
  const float* bhh_b = (const float*)d_in[13];
  const int*   eidx  = (const int*)d_in[14];
  const int* esrc = eidx;
  const int* etrg = eidx + NEDGE;
  float* out = (float*)d_out;

  unsigned char* ws = (unsigned char*)d_ws;
  unsigned int*   gmax = (unsigned int*)(ws + 0);
  unsigned int*   cnt  = (unsigned int*)(ws + 64);
  unsigned short* xh   = (unsigned short*)(ws + 256);
  unsigned short* xl   = (unsigned short*)(ws + 25600256);
  unsigned short* Gh   = (unsigned short*)(ws + 256);          // aliases xh+xl
  unsigned short* projh= (unsigned short*)(ws + 51200256);
  unsigned short* projl= (unsigned short*)(ws + 64000256);
  double*         scod = (double*)(ws + 51200256);             // aliases projh
  uint2*          sa   = (uint2*) (ws + 64000256);             // aliases projl
  unsigned short* Wch  = (unsigned short*)(ws + 76800256);
  unsigned short* Wcl  = (unsigned short*)(ws + 76931328);
  unsigned short* wihh = (unsigned short*)(ws + 77062400);
  unsigned short* wihl = (unsigned short*)(ws + 77193472);
  double*         vsrc = (double*)(ws + 77324544);
  double*         vtrg = (double*)(ws + 77326592);
  double*         ssrc = (double*)(ws + 77328640);
  double*         strg = (double*)(ws + 77728640);
  unsigned short* Pl   = (unsigned short*)(ws + 78128640);

  k0_init<<<dim3(1), dim3(64), 0, stream>>>(gmax, cnt);
  k_cvt<<<dim3((N_NODES*FIN/4 + 255)/256), dim3(256), 0, stream>>>(x, xh, xl);
  k_w<<<dim3(769), dim3(256), 0, stream>>>(Wp, Ws, wih_b, whh_b, a_src, a_trg,
                                           Wch, Wcl, wihh, wihl, Pl, vsrc, vtrg);
  k_s<<<dim3((N_NODES+255)/256), dim3(256), 0, stream>>>(x, vsrc, vtrg, ssrc, strg);
  kgemm<FIN,0><<<dim3((N_NODES+127)/128, 4), dim3(256), 0, stream>>>(
      xh, xl, Wch, Wcl, bias, out, projh, projl);
  kgemm<HID,1><<<dim3((N_NODES+127)/128, 8), dim3(256), 0, stream>>>(
      projh, projl, wihh, wihl, bias, out, Gh, (unsigned short*)0);
  k3_scores<<<dim3((N_NODES+255)/256), dim3(256), 0, stream>>>(ssrc, strg, esrc, etrg, scod, gmax);
  k4_att<<<dim3((N_NODES+255)/256), dim3(256), 0, stream>>>(scod, esrc, gmax, sa);
  hipFuncSetAttribute(reinterpret_cast<const void*>(k5_lstm),
                      hipFuncAttributeMaxDynamicSharedMemorySize, K5_LDS);
  k5_lstm<<<dim3(256), dim3(K5_THREADS), K5_LDS, stream>>>(Gh, Pl, bih_b, bhh_b, sa, cnt, out);
}

// Round 7
// 942.489 us; speedup vs baseline: 1.4066x; 1.4066x over previous
//
#include <hip/hip_runtime.h>
#include <hip/hip_bf16.h>
#include <math.h>

#define N_NODES 50000
#define DEG 16
#define FIN 256
#define FOUT 128
#define HID 128
#define FG 512            // 4*HID
#define NEDGE (N_NODES*DEG)
#define NC32 1563             // ceil(50000/32), last chunk half-full (padded in k4)

typedef __bf16 bf16x8 __attribute__((ext_vector_type(8)));
typedef float  f32x4  __attribute__((ext_vector_type(4)));
typedef float  f32x16 __attribute__((ext_vector_type(16)));

// ---------------- helpers ----------------
static __device__ __forceinline__ float u2f(unsigned int u){ union {unsigned int u; float f;} v; v.u=u; return v.f; }
static __device__ __forceinline__ unsigned int f2u(float f){ union {float f; unsigned int u;} v; v.f=f; return v.u; }
static __device__ __forceinline__ unsigned short f2bfu(float f){  // RNE float->bf16 bits
  unsigned int u = f2u(f);
  unsigned int r = u + 0x7fffu + ((u >> 16) & 1u);
  return (unsigned short)(r >> 16);
}
static __device__ __forceinline__ float bflo(unsigned int u){ return u2f(u << 16); }
static __device__ __forceinline__ float bfhi(unsigned int u){ return u2f(u & 0xffff0000u); }
static __device__ __forceinline__ float sigm(float x){ return 1.f/(1.f + __expf(-x)); }

union FU { bf16x8 bf; unsigned short us[8]; uint4 u4; };

// ---------------- K0: init global-max key + steal counter ----------------
__global__ void k0_init(unsigned int* __restrict__ gmax_key, unsigned int* __restrict__ cnt){
  if (threadIdx.x == 0) { *gmax_key = 0u; *cnt = 0u; }
}

// ---------------- KA: x -> bf16 hi/lo planes ----------------
__global__ __launch_bounds__(256) void k_cvt(
    const float* __restrict__ x, unsigned short* __restrict__ xh, unsigned short* __restrict__ xl)
{
  const int idx = blockIdx.x*256 + threadIdx.x;     // float4 granules
  if (idx >= (N_NODES*FIN)/4) return;
  const float4 v = ((const float4*)x)[idx];
  ushort4 h, l;
  h.x = f2bfu(v.x); l.x = f2bfu(v.x - u2f((unsigned)h.x << 16));
  h.y = f2bfu(v.y); l.y = f2bfu(v.y - u2f((unsigned)h.y << 16));
  h.z = f2bfu(v.z); l.z = f2bfu(v.z - u2f((unsigned)h.z << 16));
  h.w = f2bfu(v.w); l.w = f2bfu(v.w - u2f((unsigned)h.w << 16));
  ((ushort4*)xh)[idx] = h;
  ((ushort4*)xl)[idx] = l;
}

// ---------------- KW: weight converts + v = W^T a (double) + w_hh 32x32-B-frag pack ----------------
// blocks 0..255: Wcomb rows -> Wch/Wcl ; 256..511: wih -> wihh/wihl ; 512: v=W^T a
// blocks 513..768: whh [512,128] -> Pl bf16 in mfma_32x32x16 B-fragment order:
//   element (row=g*128+f, k): wave w=f>>4, ti=g>>1, lane=((k>>3)&1)*32 + (g&1)*16 + (f&15),
//   frag=(w*2+ti)*8 + (k>>4), j=k&7 -> Pl[frag*512 + lane*8 + j]
__global__ __launch_bounds__(256) void k_w(
    const float* __restrict__ Wp, const float* __restrict__ Ws,
    const float* __restrict__ wih, const float* __restrict__ whh,
    const float* __restrict__ a_src, const float* __restrict__ a_trg,
    unsigned short* __restrict__ Wch, unsigned short* __restrict__ Wcl,
    unsigned short* __restrict__ wihh, unsigned short* __restrict__ wihl,
    unsigned short* __restrict__ Pl,
    double* __restrict__ vsrc, double* __restrict__ vtrg)
{
  const int b = blockIdx.x, tid = threadIdx.x;
  if (b < 256) {
    const float* src = (b < 128) ? (Wp + b*FIN) : (Ws + (b-128)*FIN);
    const float v = src[tid];
    const unsigned short h = f2bfu(v);
    Wch[b*FIN + tid] = h;
    Wcl[b*FIN + tid] = f2bfu(v - u2f((unsigned)h << 16));
  } else if (b < 512) {
    const int row = (b-256)*2 + (tid >> 7);
    const int k   = tid & 127;
    const float v = wih[row*HID + k];
    const unsigned short h = f2bfu(v);
    wihh[row*HID + k] = h;
    wihl[row*HID + k] = f2bfu(v - u2f((unsigned)h << 16));
  } else if (b == 512) {
    const int k = tid;
    double s1 = 0.0, s2 = 0.0;
    for (int i = 0; i < FOUT; ++i) {
      const double w = (double)Wp[i*FIN + k];
      s1 += (double)a_src[i] * w;
      s2 += (double)a_trg[i] * w;
    }
    vsrc[k] = s1; vtrg[k] = s2;
  } else {
    const int idx = (b-513)*256 + tid;        // one whh element
    const int row = idx >> 7, k = idx & 127;  // row = g*128 + f
    const int g = row >> 7, f = row & 127;
    const int w = (f >> 4) & 7, ti = g >> 1, g_lo = g & 1;
    const int lane = ((k >> 3) & 1)*32 + g_lo*16 + (f & 15);
    const int frag = (w*2 + ti)*8 + (k >> 4);
    Pl[frag*512 + lane*8 + (k & 7)] = f2bfu(whh[row*HID + k]);
  }
}

// ---------------- KS: s_src/s_trg = x @ v (double) ----------------
__global__ __launch_bounds__(256) void k_s(
    const float* __restrict__ x, const double* __restrict__ vsrc, const double* __restrict__ vtrg,
    double* __restrict__ ssrc, double* __restrict__ strg)
{
  const int n = blockIdx.x*256 + threadIdx.x;
  if (n >= N_NODES) return;
  double ss = 0.0, st = 0.0;
  for (int k = 0; k < FIN; k += 4) {
    const float4 xv = *(const float4*)&x[n*FIN + k];
    ss += xv.x*vsrc[k] + xv.y*vsrc[k+1] + xv.z*vsrc[k+2] + xv.w*vsrc[k+3];
    st += xv.x*vtrg[k] + xv.y*vtrg[k+1] + xv.z*vtrg[k+2] + xv.w*vtrg[k+3];
  }
  ssrc[n] = ss; strg[n] = st;
}

// ---------------- KG: split-bf16 MFMA GEMM, 128x64 tile ----------------
// MODE 1 writes G gate-pair-interleaved: G[node][f*4+p], position p holds gate
// (p&1)*2+(p>>1)  (order i,g,f,o) so dword at f*8+g_lo*4 = (gate g_lo, gate g_lo+2).
template<int KD, int MODE>
__global__ __launch_bounds__(256) void kgemm(
    const unsigned short* __restrict__ Ah_g, const unsigned short* __restrict__ Al_g,
    const unsigned short* __restrict__ Bh_g, const unsigned short* __restrict__ Bl_g,
    const float* __restrict__ bias, float* __restrict__ outf,
    unsigned short* __restrict__ o_h, unsigned short* __restrict__ o_l)
{
  __shared__ unsigned short At[2][128*64];
  __shared__ unsigned short Bt[2][64*64];
  const int tid = threadIdx.x;
  const int bm = blockIdx.x, bn = blockIdx.y;
  const int r0 = bm*128;
  const int wave = tid >> 6, lane = tid & 63, c = lane & 15, q = lane >> 4;
  const int srow = tid >> 3, sg = tid & 7;

  f32x4 acc[2][4];
  #pragma unroll
  for (int rt = 0; rt < 2; ++rt)
    #pragma unroll
    for (int ct = 0; ct < 4; ++ct) acc[rt][ct] = (f32x4){0.f,0.f,0.f,0.f};

  for (int kt = 0; kt < KD/64; ++kt) {
    const int k0 = kt*64;
    __syncthreads();
    #pragma unroll
    for (int rr = 0; rr < 4; ++rr) {
      const int row = rr*32 + srow;
      int grow = r0 + row; if (grow >= N_NODES) grow = N_NODES-1;
      const int ga = grow*KD + k0 + sg*8;
      const int la = row*64 + (((sg ^ (row & 7))) << 3);
      *(uint4*)&At[0][la] = *(const uint4*)&Ah_g[ga];
      *(uint4*)&At[1][la] = *(const uint4*)&Al_g[ga];
    }
    #pragma unroll
    for (int rr = 0; rr < 2; ++rr) {
      const int row = rr*32 + srow;
      int wr;
      if (MODE == 0) wr = bn*64 + row;
      else {
        const int j = bn*64 + row;
        const int p = j & 3;
        wr = ((p & 1)*2 + (p >> 1))*HID + (j >> 2);   // gate perm {i,g,f,o}
      }
      const int ga = wr*KD + k0 + sg*8;
      const int la = row*64 + (((sg ^ (row & 7))) << 3);
      *(uint4*)&Bt[0][la] = *(const uint4*)&Bh_g[ga];
      *(uint4*)&Bt[1][la] = *(const uint4*)&Bl_g[ga];
    }
    __syncthreads();

    #pragma unroll
    for (int s = 0; s < 2; ++s) {
      FU Af[2][2], Bf[4][2];
      #pragma unroll
      for (int rt = 0; rt < 2; ++rt) {
        const int row = wave*32 + rt*16 + c;
        const int ad = row*64 + (((((s<<2)+q) ^ (row & 7))) << 3);
        Af[rt][0].u4 = *(const uint4*)&At[0][ad];
        Af[rt][1].u4 = *(const uint4*)&At[1][ad];
      }
      #pragma unroll
      for (int ct = 0; ct < 4; ++ct) {
        const int row = ct*16 + c;
        const int ad = row*64 + (((((s<<2)+q) ^ (row & 7))) << 3);
        Bf[ct][0].u4 = *(const uint4*)&Bt[0][ad];
        Bf[ct][1].u4 = *(const uint4*)&Bt[1][ad];
      }
      #pragma unroll
      for (int rt = 0; rt < 2; ++rt)
        #pragma unroll
        for (int ct = 0; ct < 4; ++ct) {
          acc[rt][ct] = __builtin_amdgcn_mfma_f32_16x16x32_bf16(Af[rt][0].bf, Bf[ct][0].bf, acc[rt][ct], 0,0,0);
          acc[rt][ct] = __builtin_amdgcn_mfma_f32_16x16x32_bf16(Af[rt][1].bf, Bf[ct][0].bf, acc[rt][ct], 0,0,0);
          acc[rt][ct] = __builtin_amdgcn_mfma_f32_16x16x32_bf16(Af[rt][0].bf, Bf[ct][1].bf, acc[rt][ct], 0,0,0);
        }
    }
  }
  __syncthreads();

  if (MODE == 0 && bn >= 2) {
    #pragma unroll
    for (int ct = 0; ct < 4; ++ct) {
      const int col = bn*64 + ct*16 + c - 128;
      const float bv = bias[col];
      #pragma unroll
      for (int rt = 0; rt < 2; ++rt)
        #pragma unroll
        for (int i = 0; i < 4; ++i) {
          const int row = r0 + wave*32 + rt*16 + q*4 + i;
          if (row < N_NODES) outf[row*FOUT + col] = acc[rt][ct][i] + bv;
        }
    }
  } else {
    #pragma unroll
    for (int rt = 0; rt < 2; ++rt)
      #pragma unroll
      for (int ct = 0; ct < 4; ++ct)
        #pragma unroll
        for (int i = 0; i < 4; ++i) {
          const int lrow = wave*32 + rt*16 + q*4 + i;
          const int lcol = ct*16 + c;
          const float v = acc[rt][ct][i];
          const unsigned short h = f2bfu(v);
          At[0][lrow*64 + lcol] = h;
          if (MODE == 0) At[1][lrow*64 + lcol] = f2bfu(v - u2f((unsigned)h << 16));
        }
    __syncthreads();
    const int ncols = (MODE == 0) ? FOUT : FG;
    #pragma unroll
    for (int rr = 0; rr < 4; ++rr) {
      const int row = rr*32 + srow;
      const int grow = r0 + row;
      if (grow < N_NODES) {
        const int dst = grow*ncols + bn*64 + sg*8;
        *(uint4*)&o_h[dst] = *(const uint4*)&At[0][row*64 + sg*8];
        if (MODE == 0) *(uint4*)&o_l[dst] = *(const uint4*)&At[1][row*64 + sg*8];
      }
    }
  }
}

// ---------------- K3: edge scores (double) + global max ----------------
__global__ __launch_bounds__(256) void k3_scores(
    const double* __restrict__ ssrc, const double* __restrict__ strg,
    const int* __restrict__ esrc, const int* __restrict__ etrg,
    double* __restrict__ scod, unsigned int* __restrict__ gmax_key)
{
  const int n = blockIdx.x*256 + threadIdx.x;
  float lmax = -3.0e38f;
  if (n < N_NODES) {
    const double stn = strg[etrg[n*DEG]];
    #pragma unroll
    for (int j = 0; j < DEG; ++j) {
      const int e = n*DEG + j;
      double sc = ssrc[esrc[e]] + stn;
      sc = (sc > 0.0) ? sc : 0.2*sc;
      scod[e] = sc;
      lmax = fmaxf(lmax, (float)sc);
    }
  }
  #pragma unroll
  for (int off = 32; off > 0; off >>= 1)
    lmax = fmaxf(lmax, __shfl_down(lmax, off, 64));
  __shared__ float wmax[4];
  if ((threadIdx.x & 63) == 0) wmax[threadIdx.x >> 6] = lmax;
  __syncthreads();
  if (threadIdx.x == 0) {
    const float mv = fmaxf(fmaxf(wmax[0], wmax[1]), fmaxf(wmax[2], wmax[3]));
    const unsigned int u = f2u(mv);
    const unsigned int key = (u & 0x80000000u) ? ~u : (u | 0x80000000u);
    atomicMax(gmax_key, key);
  }
}

// ---------------- K4: softmax att + descending rank -> sa[chunk32][t][pos32]={src, att-bits} ----------------
// Pads virtual nodes 50000..50015 (chunk 1562) with {src=0, att=0}.
__global__ __launch_bounds__(256) void k4_att(
    const double* __restrict__ scod, const int* __restrict__ esrc,
    const unsigned int* __restrict__ gmax_key,
    uint2* __restrict__ sa)
{
  const int n = blockIdx.x*256 + threadIdx.x;
  if (n >= 50016) return;
  const int chunk = n >> 5, pos = n & 31;
  if (n >= N_NODES) {
    #pragma unroll
    for (int r = 0; r < DEG; ++r) sa[chunk*512 + r*32 + pos] = make_uint2(0u, 0u);
    return;
  }
  const unsigned int key = *gmax_key;
  const unsigned int u = (key & 0x80000000u) ? (key ^ 0x80000000u) : ~key;
  const float gmax = u2f(u);

  double sc[DEG]; float av[DEG]; int si[DEG];
  float sum = 0.f;
  #pragma unroll
  for (int j = 0; j < DEG; ++j) {
    sc[j] = scod[n*DEG + j];
    av[j] = __expf((float)sc[j] - gmax);
    sum  += av[j];
    si[j] = esrc[n*DEG + j];
  }
  const float inv = 1.f/(sum + 1e-16f);
  #pragma unroll
  for (int j = 0; j < DEG; ++j) {
    int r = 0;
    #pragma unroll
    for (int k = 0; k < DEG; ++k)
      r += (sc[k] > sc[j]) || (sc[k] == sc[j] && k > j);
    sa[chunk*512 + r*32 + pos] = make_uint2((unsigned)si[j], f2u(av[j]*inv));
  }
}

// ---------------- K5: 32x32-MFMA LSTM, B streamed from LDS, live set <=~120 regs ----------------
// Chunk=32 nodes, block=8 waves. Wave w: cols f in [16w,16w+16) x 4 gates as two
// 32-col tiles {g0,g1},{g2,g3} (col=g_lo*16+f_lo). acc=2x16=32 regs; B read from
// the 128KB LDS table exactly once per chunk-step (no VGPR-resident weights ->
// nothing for the r3-r6 allocator pathology to spill). Gate quads recombined with
// 2 shfl_xor(16) using tanh(x)=2*sigm(2x)-1. h double-buffered 2x8KB (XOR swizzle),
// ONE barrier/step. x-gates: 1 dword gather/lane/reg from gate-pair-interleaved G,
// prefetched 1 step ahead. Block-level atomic work-stealing over 1563 chunks.
#define K5_LDS (131072 + 8192 + 8192 + 2048 + 2048 + 64)
__global__ __launch_bounds__(512) void k5_lstm(
    const unsigned short* __restrict__ Gu, const unsigned short* __restrict__ Pl,
    const float* __restrict__ bih, const float* __restrict__ bhh,
    const uint2* __restrict__ sa, unsigned int* __restrict__ cnt,
    float* __restrict__ out)
{
  extern __shared__ unsigned char smem[];
  unsigned short* Bt   = (unsigned short*)smem;                 // 128KB
  unsigned short* hb0  = (unsigned short*)(smem + 131072);      // 8KB  [32 nodes][128] swizzled
  unsigned short* hb1  = (unsigned short*)(smem + 139264);      // 8KB
  float*          attb = (float*)(smem + 147456);               // 2KB  [16t][32]
  unsigned int*   srcb = (unsigned int*)(smem + 149504);        // 2KB
  volatile unsigned int* ls = (volatile unsigned int*)(smem + 151552);

  const int tid  = threadIdx.x;
  const int wave = tid >> 6, L = tid & 63;
  const int fl = L & 15;                 // f_lo
  const int gl = (L >> 4) & 1;           // g_lo: tile gates (gl, gl+2)
  const int hf = L >> 5;                 // lane half (A/B k-half, C row group)
  const int f  = wave*16 + fl;

  { // cooperative B-table load (128 KB)
    const uint4* s4 = (const uint4*)Pl;
    uint4* d4 = (uint4*)Bt;
    for (int i = tid; i < 8192; i += 512) d4[i] = s4[i];
  }
  const float bsum0 = bih[gl*HID + f]     + bhh[gl*HID + f];
  const float bsum1 = bih[(gl+2)*HID + f] + bhh[(gl+2)*HID + f];

  const int anode = L & 31;              // A-frag row (node)
  int aoff[8];
  #pragma unroll
  for (int kt = 0; kt < 8; ++kt)
    aoff[kt] = anode*128 + ((((kt*2 + hf)) ^ (anode & 15)) & 15)*8;

  const int lane_off = f*8 + gl*4;       // byte offset within 1KB G row
  const char* Gb = (const char*)Gu;
  const uint4* Bt4 = (const uint4*)Bt;
  const int fragbase = wave*16;          // (w*2+ti)*8 + kt

  __syncthreads();                       // Bt ready

  for (;;) {
    if (tid == 0) ls[0] = atomicAdd(cnt, 1u);
    __syncthreads();
    const int c = (int)ls[0];
    if (c >= NC32) break;
    { // stage chunk's (src, att)
      const uint2 v = sa[c*512 + tid];
      srcb[tid] = v.x;
      attb[tid] = u2f(v.y);
    }
    __syncthreads();

    f32x16 acc0, acc1;
    float cst[16];
    #pragma unroll
    for (int i = 0; i < 16; ++i) cst[i] = 0.f;

    unsigned xg[16];                     // prefetched x-gate dwords (t=0)
    #pragma unroll
    for (int i = 0; i < 16; ++i) {
      const int node = (i & 3) + 8*(i >> 2) + 4*hf;
      xg[i] = *(const unsigned*)(Gb + (size_t)srcb[node]*1024 + lane_off);
    }

    #pragma unroll 1
    for (int t = 0; t < DEG; ++t) {
      // C init: bias + att * x-gate (tile0 = gate gl, tile1 = gate gl+2)
      #pragma unroll
      for (int i = 0; i < 16; ++i) {
        const int node = (i & 3) + 8*(i >> 2) + 4*hf;
        const float at = attb[t*32 + node];
        acc0[i] = bsum0 + at*bflo(xg[i]);
        acc1[i] = bsum1 + at*bfhi(xg[i]);
      }
      if (t < DEG-1) {                   // prefetch next step's x-gates
        #pragma unroll
        for (int i = 0; i < 16; ++i) {
          const int node = (i & 3) + 8*(i >> 2) + 4*hf;
          xg[i] = *(const unsigned*)(Gb + (size_t)srcb[(t+1)*32 + node]*1024 + lane_off);
        }
      }
      if (t > 0) {                       // recurrent h @ whh^T
        const unsigned short* hb = (t & 1) ? hb0 : hb1;
        #pragma unroll
        for (int kt = 0; kt < 8; ++kt) {
          FU A;  A.u4  = *(const uint4*)(hb + aoff[kt]);
          FU B0; B0.u4 = Bt4[(fragbase + kt)*64 + L];
          FU B1; B1.u4 = Bt4[(fragbase + 8 + kt)*64 + L];
          acc0 = __builtin_amdgcn_mfma_f32_32x32x16_bf16(A.bf, B0.bf, acc0, 0, 0, 0);
          acc1 = __builtin_amdgcn_mfma_f32_32x32x16_bf16(A.bf, B1.bf, acc1, 0, 0, 0);
        }
      }
      // nonlinearity: gl=0 lanes hold (i,g), gl=1 hold (f,o); 2 shfl_xor(16)
      unsigned short* hw = (t & 1) ? hb1 : hb0;
      #pragma unroll
      for (int i = 0; i < 16; ++i) {
        const float s0 = sigm(acc0[i]);                  // gl0: sigm(i) ; gl1: sigm(f)
        const float x1 = gl ? acc1[i] : 2.f*acc1[i];
        const float ss = sigm(x1);
        const float v1 = gl ? ss : 2.f*ss - 1.f;         // gl0: tanh(g) ; gl1: sigm(o)
        const float p  = s0 * v1;                        // gl0: si*tg
        const float snd = gl ? s0 : p;                   // gl1 sends sigm(f)
        const float r  = __shfl_xor(snd, 16, 64);        // gl0 receives sigm(f)
        const float cn = r*cst[i] + p;                   // valid in gl0
        cst[i] = cn;
        const float tc = 2.f*sigm(2.f*cn) - 1.f;         // tanh(c), valid gl0
        const float r2 = __shfl_xor(tc, 16, 64);         // gl1 receives tanh(c)
        const float h  = v1 * r2;                        // valid in gl1: sigm(o)*tanh(c)
        const int node = (i & 3) + 8*(i >> 2) + 4*hf;
        if (t < DEG-1) {
          if (gl) {
            const int sg = ((f >> 3) ^ (node & 15)) & 15;
            hw[node*128 + sg*8 + (f & 7)] = f2bfu(h);
          }
        } else if (gl) {
          const int row = c*32 + node;
          if (row < N_NODES) {
            const float v = h + out[row*HID + f];        // skip(+bias) staged in out
            out[row*HID + f] = (v > 0.f) ? v : 0.01f*v;
          }
        }
      }
      __syncthreads();
    }
  }
}

// ---------------- launch ----------------
// ws layout (bytes):
//  gmax @0, cnt @64 (256 total) | xh @256 (25.6M) | xl @25600256 (25.6M)  [G aliases xh+xl]
//  projh @51200256 (12.8M) [scod aliases] | projl @64000256 (12.8M) [sa (6.4M) aliases]
//  Wch @76800256  Wcl @76931328  wihh @77062400  wihl @77193472 (128K each)
//  vsrc @77324544 vtrg @77326592 (2K) | ssrc @77328640 strg @77728640 (400K each)
//  Pl @78128640 (128K)  -> end ~78.26 MB
extern "C" void kernel_launch(void* const* d_in, const int* in_sizes, int n_in,
                              void* d_out, int out_size, void* d_ws, size_t ws_size,
                              hipStream_t stream)
{
  (void)in_sizes; (void)n_in; (void)out_size; (void)ws_size;
  const float* x     = (const float*)d_in[0];
  const float* Wp    = (const float*)d_in[1];
  const float* a_src = (const float*)d_in[2];
  const float* a_trg = (const float*)d_in[3];
  const float* Ws    = (const float*)d_in[4];
  const float* bias  = (const float*)d_in[5];
  const float* wih_b = (const float*)d_in[10];
  const float* whh_b = (const float*)d_in[11];
  const float* bih_b = (const float*)d_in[12];
  const float* bhh_b = (const float*)d_in[13];
  const int*   eidx  = (const int*)d_in[14];
  const int* esrc = eidx;
  const int* etrg = eidx + NEDGE;
  float* out = (float*)d_out;

  unsigned char* ws = (unsigned char*)d_ws;
  unsigned int*   gmax = (unsigned int*)(ws + 0);
  unsigned int*   cnt  = (unsigned int*)(ws + 64);
  unsigned short* xh   = (unsigned short*)(ws + 256);
  unsigned short* xl   = (unsigned short*)(ws + 25600256);
  unsigned short* Gh   = (unsigned short*)(ws + 256);          // aliases xh+xl
  unsigned short* projh= (unsigned short*)(ws + 51200256);
  unsigned short* projl= (unsigned short*)(ws + 64000256);
  double*         scod = (double*)(ws + 51200256);             // aliases projh
  uint2*          sa   = (uint2*) (ws + 64000256);             // aliases projl
  unsigned short* Wch  = (unsigned short*)(ws + 76800256);
  unsigned short* Wcl  = (unsigned short*)(ws + 76931328);
  unsigned short* wihh = (unsigned short*)(ws + 77062400);
  unsigned short* wihl = (unsigned short*)(ws + 77193472);
  double*         vsrc = (double*)(ws + 77324544);
  double*         vtrg = (double*)(ws + 77326592);
  double*         ssrc = (double*)(ws + 77328640);
  double*         strg = (double*)(ws + 77728640);
  unsigned short* Pl   = (unsigned short*)(ws + 78128640);

  k0_init<<<dim3(1), dim3(64), 0, stream>>>(gmax, cnt);
  k_cvt<<<dim3((N_NODES*FIN/4 + 255)/256), dim3(256), 0, stream>>>(x, xh, xl);
  k_w<<<dim3(769), dim3(256), 0, stream>>>(Wp, Ws, wih_b, whh_b, a_src, a_trg,
                                           Wch, Wcl, wihh, wihl, Pl, vsrc, vtrg);
  k_s<<<dim3((N_NODES+255)/256), dim3(256), 0, stream>>>(x, vsrc, vtrg, ssrc, strg);
  kgemm<FIN,0><<<dim3((N_NODES+127)/128, 4), dim3(256), 0, stream>>>(
      xh, xl, Wch, Wcl, bias, out, projh, projl);
  kgemm<HID,1><<<dim3((N_NODES+127)/128, 8), dim3(256), 0, stream>>>(
      projh, projl, wihh, wihl, bias, out, Gh, (unsigned short*)0);
  k3_scores<<<dim3((N_NODES+255)/256), dim3(256), 0, stream>>>(ssrc, strg, esrc, etrg, scod, gmax);
  k4_att<<<dim3((50016+255)/256), dim3(256), 0, stream>>>(scod, esrc, gmax, sa);
  hipFuncSetAttribute(reinterpret_cast<const void*>(k5_lstm),
                      hipFuncAttributeMaxDynamicSharedMemorySize, K5_LDS);
  k5_lstm<<<dim3(256), dim3(512), K5_LDS, stream>>>(Gh, Pl, bih_b, bhh_b, sa, cnt, out);
}